// Round 2
// baseline (192.801 us; speedup 1.0000x reference)
//
#include <hip/hip_runtime.h>

// LocalAttention fp32: B=4, L=2048, H=16, E=D=64, window=64 (keys [q-32,q+32) clamped).
// Inputs/outputs are float32 per the reference (round-1 NaN was fp32-read-as-bf16).
//
// Block = 32-query tile for one (b,h); key strip = 96 contiguous rows.
// 256 threads = 32 queries x 8 lanes. LDS: K[96][68]f + V[96][68]f + S[32][68]f
// = 59.5 KB -> 2 blocks/CU. Stride 68 floats (272 B) keeps 16B alignment and
// rotates banks by 4 per row. Q tile is staged into S, then S is reused for scores.

#define B_ 4
#define L_ 2048
#define H_ 16
#define E_ 64
#define D_ 64
#define TQ 32
#define KT 96
#define ST 68

__global__ __launch_bounds__(256, 2)
void local_attn_kernel(const float* __restrict__ qg,
                       const float* __restrict__ kg,
                       const float* __restrict__ vg,
                       float* __restrict__ og) {
  __shared__ __align__(16) float Ks[KT * ST];
  __shared__ __align__(16) float Vs[KT * ST];
  __shared__ __align__(16) float S[TQ * ST];   // Q staging, then scores

  const int t = threadIdx.x;
  const int q0 = blockIdx.x * TQ;
  const int h = blockIdx.y;
  const int b = blockIdx.z;
  const int kstart = q0 - 32;

  // ---- Phase 0: stage K,V strip (96 rows x 64 f32) + Q tile (32 rows, into S) ----
  #pragma unroll
  for (int it = 0; it < 6; ++it) {
    int cid = t + it * 256;            // 0..1535 = 96 rows x 16 float4 chunks
    int row = cid >> 4, ch = cid & 15;
    int key = kstart + row;
    float4 kv = make_float4(0.f, 0.f, 0.f, 0.f);
    float4 vv = make_float4(0.f, 0.f, 0.f, 0.f);
    if (key >= 0 && key < L_) {
      size_t base = ((size_t)(b * L_ + key) * H_ + h) * (size_t)E_ + ch * 4;
      kv = *(const float4*)(kg + base);
      vv = *(const float4*)(vg + base);
    }
    *(float4*)&Ks[row * ST + ch * 4] = kv;
    *(float4*)&Vs[row * ST + ch * 4] = vv;
  }
  #pragma unroll
  for (int it = 0; it < 2; ++it) {
    int cid = t + it * 256;            // 0..511 = 32 rows x 16 chunks
    int row = cid >> 4, ch = cid & 15;
    size_t base = ((size_t)(b * L_ + q0 + row) * H_ + h) * (size_t)E_ + ch * 4;
    *(float4*)&S[row * ST + ch * 4] = *(const float4*)(qg + base);
  }
  __syncthreads();

  const int qi = t >> 3;   // query within tile (0..31)
  const int qt = t & 7;    // 8-lane split: keys (phase 1), dims (phase 3)

  // ---- Load Q row into registers (broadcast: 8 lanes read same row) ----
  float qreg[64];
  {
    const float4* qrow = (const float4*)&S[qi * ST];
    #pragma unroll
    for (int c = 0; c < 16; ++c) {
      float4 f = qrow[c];
      qreg[c * 4 + 0] = f.x; qreg[c * 4 + 1] = f.y;
      qreg[c * 4 + 2] = f.z; qreg[c * 4 + 3] = f.w;
    }
  }
  __syncthreads();  // all Q reads done before S is overwritten with scores

  // ---- Phase 1: scores. thread (qi,qt) does jj = qt + 8k, k=0..7 ----
  #pragma unroll
  for (int k = 0; k < 8; ++k) {
    int jj = qt + 8 * k;               // offset in this query's 64-key window
    int j = qi + jj;                   // row in the 96-row strip (max 94)
    int key = kstart + j;
    float acc = 0.f;
    const float4* krow = (const float4*)&Ks[j * ST];
    #pragma unroll
    for (int c = 0; c < 16; ++c) {
      float4 f = krow[c];
      acc = fmaf(f.x, qreg[c * 4 + 0], acc);
      acc = fmaf(f.y, qreg[c * 4 + 1], acc);
      acc = fmaf(f.z, qreg[c * 4 + 2], acc);
      acc = fmaf(f.w, qreg[c * 4 + 3], acc);
    }
    S[qi * ST + jj] = (key >= 0 && key < L_) ? acc : -1e30f;
  }
  __syncthreads();

  // ---- Phase 2: softmax over 64-entry window (8 lanes/row via shfl) ----
  {
    float vals[8];
    float* srow = &S[qi * ST + qt * 8];
    float4 a = *(float4*)&srow[0];
    float4 c = *(float4*)&srow[4];
    vals[0] = a.x; vals[1] = a.y; vals[2] = a.z; vals[3] = a.w;
    vals[4] = c.x; vals[5] = c.y; vals[6] = c.z; vals[7] = c.w;
    float m = vals[0];
    #pragma unroll
    for (int i = 1; i < 8; ++i) m = fmaxf(m, vals[i]);
    m = fmaxf(m, __shfl_xor(m, 1));
    m = fmaxf(m, __shfl_xor(m, 2));
    m = fmaxf(m, __shfl_xor(m, 4));
    float sum = 0.f;
    #pragma unroll
    for (int i = 0; i < 8; ++i) {
      vals[i] = __expf((vals[i] - m) * 0.125f);  // scale = 1/sqrt(64); -1e30 -> 0
      sum += vals[i];
    }
    sum += __shfl_xor(sum, 1);
    sum += __shfl_xor(sum, 2);
    sum += __shfl_xor(sum, 4);
    float inv = 1.0f / sum;            // >=32 valid keys always -> sum >= 1
    float4 w0 = make_float4(vals[0] * inv, vals[1] * inv, vals[2] * inv, vals[3] * inv);
    float4 w1 = make_float4(vals[4] * inv, vals[5] * inv, vals[6] * inv, vals[7] * inv);
    *(float4*)&srow[0] = w0;
    *(float4*)&srow[4] = w1;
  }
  __syncthreads();

  // ---- Phase 3: O = P*V. thread (qi,qt) owns dims [qt*8, qt*8+8) of query qi ----
  {
    const int d0 = qt * 8;
    float o[8];
    #pragma unroll
    for (int i = 0; i < 8; ++i) o[i] = 0.f;
    const float* srow = &S[qi * ST];
    #pragma unroll
    for (int jj = 0; jj < 64; ++jj) {
      float p = srow[jj];              // broadcast across the 8 lanes of this row
      int j = qi + jj;                 // invalid strip rows are zero-filled, p = 0
      const float4* vrow = (const float4*)&Vs[j * ST + d0];
      float4 a0 = vrow[0], a1 = vrow[1];
      o[0] = fmaf(p, a0.x, o[0]);
      o[1] = fmaf(p, a0.y, o[1]);
      o[2] = fmaf(p, a0.z, o[2]);
      o[3] = fmaf(p, a0.w, o[3]);
      o[4] = fmaf(p, a1.x, o[4]);
      o[5] = fmaf(p, a1.y, o[5]);
      o[6] = fmaf(p, a1.z, o[6]);
      o[7] = fmaf(p, a1.w, o[7]);
    }
    size_t base = ((size_t)(b * L_ + q0 + qi) * H_ + h) * (size_t)D_ + d0;
    *(float4*)(og + base) = make_float4(o[0], o[1], o[2], o[3]);
    *(float4*)(og + base + 4) = make_float4(o[4], o[5], o[6], o[7]);
  }
}

extern "C" void kernel_launch(void* const* d_in, const int* in_sizes, int n_in,
                              void* d_out, int out_size, void* d_ws, size_t ws_size,
                              hipStream_t stream) {
  const float* q = (const float*)d_in[0];
  const float* k = (const float*)d_in[1];
  const float* v = (const float*)d_in[2];
  float* o = (float*)d_out;
  dim3 grid(L_ / TQ, H_, B_);
  local_attn_kernel<<<grid, dim3(256), 0, stream>>>(q, k, v, o);
}

// Round 3
// 151.075 us; speedup vs baseline: 1.2762x; 1.2762x over previous
//
#include <hip/hip_runtime.h>

// LocalAttention, MFMA bf16 flash-style: B=4, L=2048, H=16, E=D=64, window=64.
// fp32 in/out; Q,K,V converted to bf16 during LDS staging; fp32 MFMA accumulate.
//
// Block = 64 queries of one (b,h); 4 waves; wave m owns 16-query M-tile m.
// Key strip = 128 rows [q0-32, q0+96). Band: query row q_rel attends relative
// keys [q_rel, q_rel+64) -> per M-tile exactly 5 key-tiles of 16 (tiles m..m+4).
// QK: A=Q (natural layout), B=K (natural layout). PV: A=P (LDS round-trip,
// zero-padded to K=96), B=V transposed [dim][key]. All MFMA fragment reads are
// ds_read_b128 with <=2-way bank aliasing (strides 72/104/152 elems).
//
// LDS: Qs 64x72 + Ks 128x72 + Vt 64x152 + P 4x16x104 (all bf16) = 60.4 KB -> 2 blk/CU.

#define B_ 4
#define L_ 2048
#define H_ 16
#define E_ 64
#define D_ 64

#define QS_STRIDE 72
#define KS_STRIDE 72
#define VT_STRIDE 152
#define P_STRIDE 104

typedef __attribute__((ext_vector_type(8))) short short8;
typedef __attribute__((ext_vector_type(4))) float f32x4;

__device__ __forceinline__ unsigned int f2bf(float x) {
  unsigned int b = __float_as_uint(x);
  b += 0x7fffu + ((b >> 16) & 1u);   // RNE to bf16
  return b >> 16;
}
__device__ __forceinline__ unsigned int pack2(float a, float b) {
  return f2bf(a) | (f2bf(b) << 16);
}

__global__ __launch_bounds__(256, 2)
void local_attn_mfma(const float* __restrict__ qg,
                     const float* __restrict__ kg,
                     const float* __restrict__ vg,
                     float* __restrict__ og) {
  __shared__ __align__(16) unsigned short Qs[64 * QS_STRIDE];
  __shared__ __align__(16) unsigned short Ks[128 * KS_STRIDE];
  __shared__ __align__(16) unsigned short Vt[64 * VT_STRIDE];
  __shared__ __align__(16) unsigned short Pl[4 * 16 * P_STRIDE];

  const int t = threadIdx.x;
  const int q0 = blockIdx.x * 64;
  const int h = blockIdx.y;
  const int b = blockIdx.z;
  const int kstart = q0 - 32;

  // ---- Stage K: 128 rows x 64 dims, fp32 -> bf16, natural layout ----
  #pragma unroll
  for (int it = 0; it < 8; ++it) {
    int cid = t + it * 256;            // 128 rows x 16 float4-chunks
    int row = cid >> 4, ch = cid & 15;
    int key = kstart + row;
    float4 f = make_float4(0.f, 0.f, 0.f, 0.f);
    if (key >= 0 && key < L_)
      f = *(const float4*)(kg + ((size_t)(b * L_ + key) * H_ + h) * E_ + ch * 4);
    uint2 p = make_uint2(pack2(f.x, f.y), pack2(f.z, f.w));
    *(uint2*)&Ks[row * KS_STRIDE + ch * 4] = p;
  }
  // ---- Stage Q: 64 rows ----
  #pragma unroll
  for (int it = 0; it < 4; ++it) {
    int cid = t + it * 256;
    int row = cid >> 4, ch = cid & 15;
    float4 f = *(const float4*)(qg + ((size_t)(b * L_ + q0 + row) * H_ + h) * E_ + ch * 4);
    uint2 p = make_uint2(pack2(f.x, f.y), pack2(f.z, f.w));
    *(uint2*)&Qs[row * QS_STRIDE + ch * 4] = p;
  }
  // ---- Stage V transposed: Vt[dim][key_rel], key pair per u32 write ----
  {
    int kp = t >> 2;                   // key pair 0..63 -> keys 2kp, 2kp+1
    int dq = t & 3;                    // dim quarter: dims dq*16 .. dq*16+15
    int k0 = kstart + 2 * kp, k1 = k0 + 1;
    float4 a[4], c[4];
    #pragma unroll
    for (int i = 0; i < 4; ++i) {
      a[i] = make_float4(0.f, 0.f, 0.f, 0.f);
      c[i] = make_float4(0.f, 0.f, 0.f, 0.f);
    }
    if (k0 >= 0 && k0 < L_) {
      const float* p = vg + ((size_t)(b * L_ + k0) * H_ + h) * D_ + dq * 16;
      #pragma unroll
      for (int i = 0; i < 4; ++i) a[i] = *(const float4*)(p + i * 4);
    }
    if (k1 >= 0 && k1 < L_) {
      const float* p = vg + ((size_t)(b * L_ + k1) * H_ + h) * D_ + dq * 16;
      #pragma unroll
      for (int i = 0; i < 4; ++i) c[i] = *(const float4*)(p + i * 4);
    }
    #pragma unroll
    for (int i = 0; i < 4; ++i) {
      float av[4] = {a[i].x, a[i].y, a[i].z, a[i].w};
      float cv[4] = {c[i].x, c[i].y, c[i].z, c[i].w};
      #pragma unroll
      for (int j = 0; j < 4; ++j) {
        int d = dq * 16 + i * 4 + j;
        *(unsigned int*)&Vt[d * VT_STRIDE + 2 * kp] = pack2(av[j], cv[j]);
      }
    }
    // zero pad: Vt cols 128..143 (read by PV k-overhang, must be finite)
    int zr = t >> 2, zc = 128 + (t & 3) * 4;
    *(uint2*)&Vt[zr * VT_STRIDE + zc] = make_uint2(0u, 0u);
  }
  __syncthreads();

  const int wave = t >> 6;             // M-tile index 0..3
  const int lane = t & 63;
  const int col16 = lane & 15;
  const int quad = lane >> 4;

  // ---- A-frags: Q M-tile. A[m][k]: m=lane&15, k=quad*8+j ----
  const short8 qa0 = *(const short8*)&Qs[(wave * 16 + col16) * QS_STRIDE + quad * 8];
  const short8 qa1 = *(const short8*)&Qs[(wave * 16 + col16) * QS_STRIDE + quad * 8 + 32];

  // ---- QK: 5 key-tiles (relative tiles wave..wave+4) ----
  f32x4 acc[5];
  #pragma unroll
  for (int tt = 0; tt < 5; ++tt) {
    int krow = wave * 16 + tt * 16 + col16;   // B: n=lane&15 (key), k=quad*8+j (E)
    short8 b0 = *(const short8*)&Ks[krow * KS_STRIDE + quad * 8];
    short8 b1 = *(const short8*)&Ks[krow * KS_STRIDE + quad * 8 + 32];
    f32x4 c = {0.f, 0.f, 0.f, 0.f};
    c = __builtin_amdgcn_mfma_f32_16x16x32_bf16(qa0, b0, c, 0, 0, 0);
    c = __builtin_amdgcn_mfma_f32_16x16x32_bf16(qa1, b1, c, 0, 0, 0);
    acc[tt] = c;
  }

  // ---- Mask + softmax in registers. C layout: row=quad*4+r (query), col=lane&15 ----
  #pragma unroll
  for (int r = 0; r < 4; ++r) {
    const int row_loc = quad * 4 + r;
    float x[5];
    #pragma unroll
    for (int tt = 0; tt < 5; ++tt) {
      int c_loc = tt * 16 + col16;                    // key rel to M-tile start
      int gkey = kstart + wave * 16 + c_loc;          // global key
      bool ok = (c_loc >= row_loc) && (c_loc < row_loc + 64) && (gkey >= 0) && (gkey < L_);
      x[tt] = ok ? acc[tt][r] * 0.125f : -1e30f;      // scale = 1/sqrt(64)
    }
    float m = fmaxf(fmaxf(fmaxf(x[0], x[1]), fmaxf(x[2], x[3])), x[4]);
    m = fmaxf(m, __shfl_xor(m, 1));
    m = fmaxf(m, __shfl_xor(m, 2));
    m = fmaxf(m, __shfl_xor(m, 4));
    m = fmaxf(m, __shfl_xor(m, 8));
    float s = 0.f;
    #pragma unroll
    for (int tt = 0; tt < 5; ++tt) { x[tt] = __expf(x[tt] - m); s += x[tt]; }
    s += __shfl_xor(s, 1);
    s += __shfl_xor(s, 2);
    s += __shfl_xor(s, 4);
    s += __shfl_xor(s, 8);
    float inv = 1.0f / s;              // >= 32 valid keys -> s >= 1
    #pragma unroll
    for (int tt = 0; tt < 5; ++tt) acc[tt][r] = x[tt] * inv;
  }

  // ---- P -> LDS (bf16, A-layout target), zero-pad cols 80..95 ----
  unsigned short* Pw = &Pl[wave * 16 * P_STRIDE];
  *(uint2*)&Pw[col16 * P_STRIDE + 80 + quad * 4] = make_uint2(0u, 0u);
  #pragma unroll
  for (int tt = 0; tt < 5; ++tt)
    #pragma unroll
    for (int r = 0; r < 4; ++r)
      Pw[(quad * 4 + r) * P_STRIDE + tt * 16 + col16] = (unsigned short)f2bf(acc[tt][r]);

  // ---- PV: A=P[16 x 96], B=Vt keys [wave*16, wave*16+96) x 64 dims ----
  f32x4 oacc[4];
  #pragma unroll
  for (int nt = 0; nt < 4; ++nt) oacc[nt] = (f32x4){0.f, 0.f, 0.f, 0.f};
  #pragma unroll
  for (int ks = 0; ks < 3; ++ks) {
    short8 pa = *(const short8*)&Pw[col16 * P_STRIDE + ks * 32 + quad * 8];
    #pragma unroll
    for (int nt = 0; nt < 4; ++nt) {
      short8 vb = *(const short8*)&Vt[(nt * 16 + col16) * VT_STRIDE + wave * 16 + ks * 32 + quad * 8];
      oacc[nt] = __builtin_amdgcn_mfma_f32_16x16x32_bf16(pa, vb, oacc[nt], 0, 0, 0);
    }
  }

  // ---- Store O (fp32). C layout: row=quad*4+r (query), col=lane&15 (dim base) ----
  #pragma unroll
  for (int r = 0; r < 4; ++r) {
    int q = q0 + wave * 16 + quad * 4 + r;
    float* orow = og + ((size_t)(b * L_ + q) * H_ + h) * D_;
    #pragma unroll
    for (int nt = 0; nt < 4; ++nt)
      orow[nt * 16 + col16] = oacc[nt][r];
  }
}

extern "C" void kernel_launch(void* const* d_in, const int* in_sizes, int n_in,
                              void* d_out, int out_size, void* d_ws, size_t ws_size,
                              hipStream_t stream) {
  const float* q = (const float*)d_in[0];
  const float* k = (const float*)d_in[1];
  const float* v = (const float*)d_in[2];
  float* o = (float*)d_out;
  dim3 grid(L_ / 64, H_, B_);
  local_attn_mfma<<<grid, dim3(256), 0, stream>>>(q, k, v, o);
}

// Round 4
// 148.322 us; speedup vs baseline: 1.2999x; 1.0186x over previous
//
#include <hip/hip_runtime.h>

// LocalAttention, MFMA bf16 flash-style, round 4: B=4, L=2048, H=16, E=D=64, window=64.
// fp32 in/out; bf16 MFMA compute, fp32 accumulate.
//
// Round-4 change vs round 3: Q and K fragments are loaded DIRECTLY from global
// into registers (fragment k-dims are 8 contiguous elements -> 2x float4 + pack),
// so LDS holds only Vt (transposed V) + P = 32 KB exactly -> 4 blocks/CU
// co-resident (was 2 at 60 KB), halving the number of exposed staging rounds.
// Only V staging needs the barrier; Q/K load latency hides under it.
//
// Block = 64 queries of one (b,h); wave m owns 16-query M-tile m; key strip
// [q0-32, q0+96). Per M-tile the window covers exactly 5 16-key tiles (m..m+4).

#define B_ 4
#define L_ 2048
#define H_ 16
#define E_ 64
#define D_ 64
#define VT_STRIDE 152
#define P_STRIDE 104

typedef __attribute__((ext_vector_type(8))) short short8;
typedef __attribute__((ext_vector_type(4))) float f32x4;

__device__ __forceinline__ unsigned int f2bf(float x) {
  unsigned int b = __float_as_uint(x);
  b += 0x7fffu + ((b >> 16) & 1u);   // RNE to bf16
  return b >> 16;
}
__device__ __forceinline__ unsigned int pack2(float a, float b) {
  return f2bf(a) | (f2bf(b) << 16);
}
__device__ __forceinline__ short8 pack8(const float4& a, const float4& b) {
  union { short8 s; uint4 u; } r;
  r.u = make_uint4(pack2(a.x, a.y), pack2(a.z, a.w), pack2(b.x, b.y), pack2(b.z, b.w));
  return r.s;
}

__global__ __launch_bounds__(256, 4)
void local_attn_mfma(const float* __restrict__ qg,
                     const float* __restrict__ kg,
                     const float* __restrict__ vg,
                     float* __restrict__ og) {
  __shared__ __align__(16) unsigned short Vt[64 * VT_STRIDE];    // [dim][key_rel] bf16
  __shared__ __align__(16) unsigned short Pl[4 * 16 * P_STRIDE]; // per-wave P tile

  const int t = threadIdx.x;
  const int q0 = blockIdx.x * 64;
  const int h = blockIdx.y;
  const int b = blockIdx.z;
  const int kstart = q0 - 32;
  const int wave = t >> 6;
  const int lane = t & 63;
  const int col16 = lane & 15;
  const int quad = lane >> 4;

  // ---- Stage V transposed: thread = 4 keys x 8 dims; ds_write_b64, <=2-way banks ----
  {
    const int kq = t & 31;             // key group: keys kstart + 4*kq .. +3
    const int dg = t >> 5;             // dim group: dims dg*8 .. +7
    float va[4][8];
    #pragma unroll
    for (int u = 0; u < 4; ++u) {
      int key = kstart + 4 * kq + u;
      float4 fa = make_float4(0.f, 0.f, 0.f, 0.f);
      float4 fb = make_float4(0.f, 0.f, 0.f, 0.f);
      if (key >= 0 && key < L_) {
        const float* p = vg + ((size_t)(b * L_ + key) * H_ + h) * D_ + dg * 8;
        fa = *(const float4*)p;
        fb = *(const float4*)(p + 4);
      }
      va[u][0] = fa.x; va[u][1] = fa.y; va[u][2] = fa.z; va[u][3] = fa.w;
      va[u][4] = fb.x; va[u][5] = fb.y; va[u][6] = fb.z; va[u][7] = fb.w;
    }
    #pragma unroll
    for (int i = 0; i < 8; ++i) {
      uint2 w = make_uint2(pack2(va[0][i], va[1][i]), pack2(va[2][i], va[3][i]));
      *(uint2*)&Vt[(dg * 8 + i) * VT_STRIDE + 4 * kq] = w;
    }
    // zero pad key cols 128..143 (PV K-overhang reads them; P there is 0)
    *(uint2*)&Vt[(t >> 2) * VT_STRIDE + 128 + (t & 3) * 4] = make_uint2(0u, 0u);
  }

  // ---- Q A-frags direct from global: A[m=col16][k=quad*8+j (+32)] ----
  short8 qa0, qa1;
  {
    const float* p = qg + ((size_t)(b * L_ + q0 + wave * 16 + col16) * H_ + h) * E_ + quad * 8;
    float4 a0 = *(const float4*)p;
    float4 a1 = *(const float4*)(p + 4);
    float4 a2 = *(const float4*)(p + 32);
    float4 a3 = *(const float4*)(p + 36);
    qa0 = pack8(a0, a1);
    qa1 = pack8(a2, a3);
  }

  // ---- K B-frags direct from global: B[n=col16 (key), k=quad*8+j (+32)] ----
  short8 kb0[5], kb1[5];
  #pragma unroll
  for (int tt = 0; tt < 5; ++tt) {
    int key = kstart + wave * 16 + tt * 16 + col16;
    float4 a0 = make_float4(0.f, 0.f, 0.f, 0.f);
    float4 a1 = a0, a2 = a0, a3 = a0;
    if (key >= 0 && key < L_) {
      const float* p = kg + ((size_t)(b * L_ + key) * H_ + h) * E_ + quad * 8;
      a0 = *(const float4*)p;
      a1 = *(const float4*)(p + 4);
      a2 = *(const float4*)(p + 32);
      a3 = *(const float4*)(p + 36);
    }
    kb0[tt] = pack8(a0, a1);
    kb1[tt] = pack8(a2, a3);
  }
  __syncthreads();   // Vt ready (Q/K latency hidden under this wait)

  // ---- QK: 5 key-tiles ----
  f32x4 acc[5];
  #pragma unroll
  for (int tt = 0; tt < 5; ++tt) {
    f32x4 c = {0.f, 0.f, 0.f, 0.f};
    c = __builtin_amdgcn_mfma_f32_16x16x32_bf16(qa0, kb0[tt], c, 0, 0, 0);
    c = __builtin_amdgcn_mfma_f32_16x16x32_bf16(qa1, kb1[tt], c, 0, 0, 0);
    acc[tt] = c;
  }

  // ---- Mask + softmax in registers. C layout: row=quad*4+r (query), col=col16 ----
  #pragma unroll
  for (int r = 0; r < 4; ++r) {
    const int row_loc = quad * 4 + r;
    float x[5];
    #pragma unroll
    for (int tt = 0; tt < 5; ++tt) {
      int c_loc = tt * 16 + col16;                    // key rel to M-tile start
      int gkey = kstart + wave * 16 + c_loc;          // global key
      bool ok = (c_loc >= row_loc) && (c_loc < row_loc + 64) && (gkey >= 0) && (gkey < L_);
      x[tt] = ok ? acc[tt][r] * 0.125f : -1e30f;      // scale = 1/sqrt(64)
    }
    float m = fmaxf(fmaxf(fmaxf(x[0], x[1]), fmaxf(x[2], x[3])), x[4]);
    m = fmaxf(m, __shfl_xor(m, 1));
    m = fmaxf(m, __shfl_xor(m, 2));
    m = fmaxf(m, __shfl_xor(m, 4));
    m = fmaxf(m, __shfl_xor(m, 8));
    float s = 0.f;
    #pragma unroll
    for (int tt = 0; tt < 5; ++tt) { x[tt] = __expf(x[tt] - m); s += x[tt]; }
    s += __shfl_xor(s, 1);
    s += __shfl_xor(s, 2);
    s += __shfl_xor(s, 4);
    s += __shfl_xor(s, 8);
    float inv = 1.0f / s;              // >= 32 valid keys -> s >= 1
    #pragma unroll
    for (int tt = 0; tt < 5; ++tt) acc[tt][r] = x[tt] * inv;
  }

  // ---- P -> LDS (bf16, A-layout target), zero-pad cols 80..95 ----
  unsigned short* Pw = &Pl[wave * 16 * P_STRIDE];
  *(uint2*)&Pw[col16 * P_STRIDE + 80 + quad * 4] = make_uint2(0u, 0u);
  #pragma unroll
  for (int tt = 0; tt < 5; ++tt)
    #pragma unroll
    for (int r = 0; r < 4; ++r)
      Pw[(quad * 4 + r) * P_STRIDE + tt * 16 + col16] = (unsigned short)f2bf(acc[tt][r]);

  // ---- PV: A=P[16 x 96], B=Vt keys [wave*16, wave*16+96) x 64 dims ----
  f32x4 oacc[4];
  #pragma unroll
  for (int nt = 0; nt < 4; ++nt) oacc[nt] = (f32x4){0.f, 0.f, 0.f, 0.f};
  #pragma unroll
  for (int ks = 0; ks < 3; ++ks) {
    short8 pa = *(const short8*)&Pw[col16 * P_STRIDE + ks * 32 + quad * 8];
    #pragma unroll
    for (int nt = 0; nt < 4; ++nt) {
      short8 vb = *(const short8*)&Vt[(nt * 16 + col16) * VT_STRIDE + wave * 16 + ks * 32 + quad * 8];
      oacc[nt] = __builtin_amdgcn_mfma_f32_16x16x32_bf16(pa, vb, oacc[nt], 0, 0, 0);
    }
  }

  // ---- Store O (fp32). C layout: row=quad*4+r (query), col=col16 (dim base) ----
  #pragma unroll
  for (int r = 0; r < 4; ++r) {
    int q = q0 + wave * 16 + quad * 4 + r;
    float* orow = og + ((size_t)(b * L_ + q) * H_ + h) * D_;
    #pragma unroll
    for (int nt = 0; nt < 4; ++nt)
      orow[nt * 16 + col16] = oacc[nt][r];
  }
}

extern "C" void kernel_launch(void* const* d_in, const int* in_sizes, int n_in,
                              void* d_out, int out_size, void* d_ws, size_t ws_size,
                              hipStream_t stream) {
  const float* q = (const float*)d_in[0];
  const float* k = (const float*)d_in[1];
  const float* v = (const float*)d_in[2];
  float* o = (float*)d_out;
  dim3 grid(L_ / 64, H_, B_);
  local_attn_mfma<<<grid, dim3(256), 0, stream>>>(q, k, v, o);
}

// Round 5
// 141.426 us; speedup vs baseline: 1.3633x; 1.0488x over previous
//
#include <hip/hip_runtime.h>

// LocalAttention, MFMA bf16 flash-style, round 5: B=4, L=2048, H=16, E=D=64, window=64.
// fp32 in/out; bf16 MFMA compute, fp32 accumulate.
//
// Round-5 = round-3 coalesced staging + round-4 small-LDS co-residency:
//   - K staged coalesced (16 lanes sweep one 256B row) -> LDS natural layout.
//   - V staged round-3 style (2 keys x full row per 4 lanes) -> LDS transposed.
//   - Q A-frags direct from global (4 insts/thread; each Q row read once).
//   - All global loads issued into registers BEFORE packs/LDS writes.
// LDS = Ks 128x72 + Vt 64x152 + P 4x16x104 (bf16) = 50 KB -> 3 blocks/CU.
//
// Block = 64 queries of one (b,h); wave m owns 16-query M-tile m; key strip
// [q0-32, q0+96). Per M-tile the window covers exactly 5 16-key tiles (m..m+4).

#define B_ 4
#define L_ 2048
#define H_ 16
#define E_ 64
#define D_ 64
#define KS_STRIDE 72
#define VT_STRIDE 152
#define P_STRIDE 104

typedef __attribute__((ext_vector_type(8))) short short8;
typedef __attribute__((ext_vector_type(4))) float f32x4;

__device__ __forceinline__ unsigned int f2bf(float x) {
  unsigned int b = __float_as_uint(x);
  b += 0x7fffu + ((b >> 16) & 1u);   // RNE to bf16
  return b >> 16;
}
__device__ __forceinline__ unsigned int pack2(float a, float b) {
  return f2bf(a) | (f2bf(b) << 16);
}
__device__ __forceinline__ short8 pack8(const float4& a, const float4& b) {
  union { short8 s; uint4 u; } r;
  r.u = make_uint4(pack2(a.x, a.y), pack2(a.z, a.w), pack2(b.x, b.y), pack2(b.z, b.w));
  return r.s;
}

__global__ __launch_bounds__(256, 3)
void local_attn_mfma(const float* __restrict__ qg,
                     const float* __restrict__ kg,
                     const float* __restrict__ vg,
                     float* __restrict__ og) {
  __shared__ __align__(16) unsigned short Ks[128 * KS_STRIDE];   // [key_rel][dim]
  __shared__ __align__(16) unsigned short Vt[64 * VT_STRIDE];    // [dim][key_rel]
  __shared__ __align__(16) unsigned short Pl[4 * 16 * P_STRIDE]; // per-wave P tile

  const int t = threadIdx.x;
  const int q0 = blockIdx.x * 64;
  const int h = blockIdx.y;
  const int b = blockIdx.z;
  const int kstart = q0 - 32;
  const int wave = t >> 6;
  const int lane = t & 63;
  const int col16 = lane & 15;
  const int quad = lane >> 4;

  const float4 fzero = make_float4(0.f, 0.f, 0.f, 0.f);

  // ---- Issue ALL global loads first (coalesced K, round-3 V, direct Q) ----
  // K: coalesced — 16 consecutive lanes sweep one 64-float row.
  float4 kf[8];
  #pragma unroll
  for (int it = 0; it < 8; ++it) {
    int cid = t + it * 256;            // 128 rows x 16 float4-chunks
    int row = cid >> 4, ch = cid & 15;
    int key = kstart + row;
    kf[it] = (key >= 0 && key < L_)
      ? *(const float4*)(kg + ((size_t)(b * L_ + key) * H_ + h) * E_ + ch * 4)
      : fzero;
  }
  // V: 4 lanes cover one key row (2 keys/thread x 4-chunk quarters).
  const int kp = t >> 2;               // key pair -> keys kstart+2kp, +2kp+1
  const int dq = t & 3;                // dim quarter: dims dq*16 .. +15
  float4 va[4], vc[4];
  {
    int k0 = kstart + 2 * kp, k1 = k0 + 1;
    #pragma unroll
    for (int i = 0; i < 4; ++i) { va[i] = fzero; vc[i] = fzero; }
    if (k0 >= 0 && k0 < L_) {
      const float* p = vg + ((size_t)(b * L_ + k0) * H_ + h) * D_ + dq * 16;
      #pragma unroll
      for (int i = 0; i < 4; ++i) va[i] = *(const float4*)(p + i * 4);
    }
    if (k1 >= 0 && k1 < L_) {
      const float* p = vg + ((size_t)(b * L_ + k1) * H_ + h) * D_ + dq * 16;
      #pragma unroll
      for (int i = 0; i < 4; ++i) vc[i] = *(const float4*)(p + i * 4);
    }
  }
  // Q A-frags direct: A[m=col16][k=quad*8+j (+32)] — one row-read per lane.
  float4 qf0, qf1, qf2, qf3;
  {
    const float* p = qg + ((size_t)(b * L_ + q0 + wave * 16 + col16) * H_ + h) * E_ + quad * 8;
    qf0 = *(const float4*)p;
    qf1 = *(const float4*)(p + 4);
    qf2 = *(const float4*)(p + 32);
    qf3 = *(const float4*)(p + 36);
  }

  // ---- Pack + LDS writes ----
  #pragma unroll
  for (int it = 0; it < 8; ++it) {
    int cid = t + it * 256;
    int row = cid >> 4, ch = cid & 15;
    float4 f = kf[it];
    *(uint2*)&Ks[row * KS_STRIDE + ch * 4] = make_uint2(pack2(f.x, f.y), pack2(f.z, f.w));
  }
  #pragma unroll
  for (int i = 0; i < 4; ++i) {
    float av[4] = {va[i].x, va[i].y, va[i].z, va[i].w};
    float cv[4] = {vc[i].x, vc[i].y, vc[i].z, vc[i].w};
    #pragma unroll
    for (int j = 0; j < 4; ++j) {
      int d = dq * 16 + i * 4 + j;
      *(unsigned int*)&Vt[d * VT_STRIDE + 2 * kp] = pack2(av[j], cv[j]);
    }
  }
  // zero pad Vt key cols 128..143 (PV K-overhang reads them; P there is 0)
  *(uint2*)&Vt[(t >> 2) * VT_STRIDE + 128 + (t & 3) * 4] = make_uint2(0u, 0u);

  const short8 qa0 = pack8(qf0, qf1);
  const short8 qa1 = pack8(qf2, qf3);
  __syncthreads();

  // ---- QK: 5 key-tiles; B-frags from Ks (ds_read_b128) ----
  f32x4 acc[5];
  #pragma unroll
  for (int tt = 0; tt < 5; ++tt) {
    int krow = wave * 16 + tt * 16 + col16;     // B: n=key, k=quad*8+j (E-dim)
    short8 b0 = *(const short8*)&Ks[krow * KS_STRIDE + quad * 8];
    short8 b1 = *(const short8*)&Ks[krow * KS_STRIDE + quad * 8 + 32];
    f32x4 c = {0.f, 0.f, 0.f, 0.f};
    c = __builtin_amdgcn_mfma_f32_16x16x32_bf16(qa0, b0, c, 0, 0, 0);
    c = __builtin_amdgcn_mfma_f32_16x16x32_bf16(qa1, b1, c, 0, 0, 0);
    acc[tt] = c;
  }

  // ---- Mask + softmax in registers. C layout: row=quad*4+r, col=col16 ----
  #pragma unroll
  for (int r = 0; r < 4; ++r) {
    const int row_loc = quad * 4 + r;
    float x[5];
    #pragma unroll
    for (int tt = 0; tt < 5; ++tt) {
      int c_loc = tt * 16 + col16;                    // key rel to M-tile start
      int gkey = kstart + wave * 16 + c_loc;          // global key
      bool ok = (c_loc >= row_loc) && (c_loc < row_loc + 64) && (gkey >= 0) && (gkey < L_);
      x[tt] = ok ? acc[tt][r] * 0.125f : -1e30f;      // scale = 1/sqrt(64)
    }
    float m = fmaxf(fmaxf(fmaxf(x[0], x[1]), fmaxf(x[2], x[3])), x[4]);
    m = fmaxf(m, __shfl_xor(m, 1));
    m = fmaxf(m, __shfl_xor(m, 2));
    m = fmaxf(m, __shfl_xor(m, 4));
    m = fmaxf(m, __shfl_xor(m, 8));
    float s = 0.f;
    #pragma unroll
    for (int tt = 0; tt < 5; ++tt) { x[tt] = __expf(x[tt] - m); s += x[tt]; }
    s += __shfl_xor(s, 1);
    s += __shfl_xor(s, 2);
    s += __shfl_xor(s, 4);
    s += __shfl_xor(s, 8);
    float inv = 1.0f / s;              // >= 32 valid keys -> s >= 1
    #pragma unroll
    for (int tt = 0; tt < 5; ++tt) acc[tt][r] = x[tt] * inv;
  }

  // ---- P -> LDS (bf16, A-layout target), zero-pad cols 80..95 ----
  unsigned short* Pw = &Pl[wave * 16 * P_STRIDE];
  *(uint2*)&Pw[col16 * P_STRIDE + 80 + quad * 4] = make_uint2(0u, 0u);
  #pragma unroll
  for (int tt = 0; tt < 5; ++tt)
    #pragma unroll
    for (int r = 0; r < 4; ++r)
      Pw[(quad * 4 + r) * P_STRIDE + tt * 16 + col16] = (unsigned short)f2bf(acc[tt][r]);

  // ---- PV: A=P[16 x 96], B=Vt keys [wave*16, wave*16+96) x 64 dims ----
  f32x4 oacc[4];
  #pragma unroll
  for (int nt = 0; nt < 4; ++nt) oacc[nt] = (f32x4){0.f, 0.f, 0.f, 0.f};
  #pragma unroll
  for (int ks = 0; ks < 3; ++ks) {
    short8 pa = *(const short8*)&Pw[col16 * P_STRIDE + ks * 32 + quad * 8];
    #pragma unroll
    for (int nt = 0; nt < 4; ++nt) {
      short8 vb = *(const short8*)&Vt[(nt * 16 + col16) * VT_STRIDE + wave * 16 + ks * 32 + quad * 8];
      oacc[nt] = __builtin_amdgcn_mfma_f32_16x16x32_bf16(pa, vb, oacc[nt], 0, 0, 0);
    }
  }

  // ---- Store O (fp32). C layout: row=quad*4+r (query), col=col16 (dim base) ----
  #pragma unroll
  for (int r = 0; r < 4; ++r) {
    int q = q0 + wave * 16 + quad * 4 + r;
    float* orow = og + ((size_t)(b * L_ + q) * H_ + h) * D_;
    #pragma unroll
    for (int nt = 0; nt < 4; ++nt)
      orow[nt * 16 + col16] = oacc[nt][r];
  }
}

extern "C" void kernel_launch(void* const* d_in, const int* in_sizes, int n_in,
                              void* d_out, int out_size, void* d_ws, size_t ws_size,
                              hipStream_t stream) {
  const float* q = (const float*)d_in[0];
  const float* k = (const float*)d_in[1];
  const float* v = (const float*)d_in[2];
  float* o = (float*)d_out;
  dim3 grid(L_ / 64, H_, B_);
  local_attn_mfma<<<grid, dim3(256), 0, stream>>>(q, k, v, o);
}